// Round 4
// baseline (185.825 us; speedup 1.0000x reference)
//
#include <hip/hip_runtime.h>
#include <math.h>

#ifndef __has_builtin
#define __has_builtin(x) 0
#endif
#if __has_builtin(__builtin_amdgcn_exp2f)
#define EXP2F(x) __builtin_amdgcn_exp2f(x)
#else
#define EXP2F(x) exp2f(x)
#endif

#define L2E  1.44269504088896340736f
#define RL2E 0.69314718055994530942f
#define GEXPC (-L2E / 72.0f)

#define NBATCH 2
#define NC 21
#define NP 4096
#define KR 35
#define NUM_ITER 5
#define CHUNK 256

typedef _Float16 half_t;
typedef _Float16 h8 __attribute__((ext_vector_type(8)));
typedef float f4 __attribute__((ext_vector_type(4)));
typedef float f2 __attribute__((ext_vector_type(2)));
#define MFMA16(a, b, c) __builtin_amdgcn_mfma_f32_16x16x32_f16((a), (b), (c), 0, 0, 0)

// packed fp32 math via inline asm (builtin lowering NaN'd — R8/R13)
static __device__ __forceinline__ f2 pk_fma(f2 a, f2 b, f2 c) {
    f2 d;
    asm volatile("v_pk_fma_f32 %0, %1, %2, %3" : "=v"(d) : "v"(a), "v"(b), "v"(c));
    return d;
}
static __device__ __forceinline__ f2 pk_add(f2 a, f2 b) {
    f2 d;
    asm volatile("v_pk_add_f32 %0, %1, %2" : "=v"(d) : "v"(a), "v"(b));
    return d;
}

// ---- ws layout (float offsets) ----
#define OFF_QFEAT 0          // [8192][8] fp32 AoS p-features
#define OFF_QSOA  65536      // [6][8192] fp32 SoA q-feature planes
#define OFF_UT    114688     // [8192][24] fp32 log-unary
#define OFF_QA    311296     // [2][24][4096] fp16 q ping
#define OFF_QB    409600     // [2][24][4096] fp16 q pong
#define OFF_G     507904     // 1 float: 1 - 2*log2(s)  (conv normalizer)
#define OFF_KMAT  524288     // 65536 frags * 512 halves = 64 MB fp16 M-matrix

#define QLS_STRIDE 264       // halves (256 data + 8 pad) — R6-proven banking

__global__ __launch_bounds__(256) void setup_kernel(
    const float* __restrict__ unary, const float* __restrict__ ref,
    const float* __restrict__ kstd, float* __restrict__ ws)
{
    int gid = blockIdx.x * 256 + threadIdx.x;
    if (gid == 0) {
        float s = 0.f;
        for (int t = -KR; t <= KR; ++t) s += expf(-(float)(t * t) * (1.0f / 72.0f));
        ws[OFF_G] = 1.0f - 2.0f * log2f(s);   // exp2 offset for 2*G2d
    }
    if (gid >= NBATCH * NP) return;
    int n = gid >> 12, p = gid & (NP - 1);
    int y = p >> 6, x = p & 63;
    float k0 = kstd[0], k1 = kstd[1], k2 = kstd[2], k3 = kstd[3], k4 = kstd[4];
    const float* rp = ref + n * 3 * NP + p;
    float f0 = (float)y / k0;
    float f1 = (float)x / k1;
    float f2_ = rp[0]      / k2;
    float f3 = rp[NP]     / k3;
    float f4_ = rp[2 * NP] / k4;
    float sq = f0*f0 + f1*f1 + f2_*f2_ + f3*f3 + f4_*f4_;
    float h  = -0.5f * L2E * sq;
    float* qf = ws + OFF_QFEAT + gid * 8;
    qf[0]=L2E*f0; qf[1]=L2E*f1; qf[2]=L2E*f2_; qf[3]=L2E*f3; qf[4]=L2E*f4_;
    qf[5]=h; qf[6]=0.f; qf[7]=0.f;
    float* qs = ws + OFF_QSOA;
    qs[0*8192 + gid] = L2E*f0;  qs[1*8192 + gid] = L2E*f1;
    qs[2*8192 + gid] = L2E*f2_; qs[3*8192 + gid] = L2E*f3;
    qs[4*8192 + gid] = L2E*f4_; qs[5*8192 + gid] = h;

    float U[NC], e[NC];
    const float* up = unary + n * NC * NP + p;
    float m = -1e30f;
    for (int c = 0; c < NC; ++c) {
        float u = up[c * NP];
        u = fminf(fmaxf(u, 1e-5f), 1.0f);
        U[c] = logf(u);
        m = fmaxf(m, U[c]);
    }
    float ssum = 0.f;
    for (int c = 0; c < NC; ++c) { e[c] = EXP2F(L2E * (U[c] - m)); ssum += e[c]; }
    float inv = 1.0f / ssum;
    float* ut = ws + OFF_UT + gid * 24;
    half_t* qh = (half_t*)(ws + OFF_QA);
    for (int c = 0; c < NC; ++c) {
        float qv = e[c] * inv;
        ut[c] = U[c];
        qh[(n * 24 + c) * NP + p] = (half_t)qv;
    }
}

// ==========================================================================
// One dispatch per CRF iteration. 256 blocks x 512 threads.
// Block (n, ptA): 32 p-rows; sweeps all 4096 q in 16 LDS-double-buffered
// chunks. Wave v owns MFMA k-step v of each chunk.
//   first: build M = 4*K + 2*G2d fragments (exp chain) -> kmat, and use them.
//   else : stream fragments from kmat (L3-resident, 64 MB), prefetch 1 ahead.
// fp32 accumulators end-to-end; cross-wave LDS reduce; softmax update fused.
// q double-buffered across dispatches (qin -> qout) to avoid R/W races.
// LDS: qlsA/B [32][264] fp16 @0/16896; qsoA/B [6][256] f32 @33792/39936.
// Epilogue reuses [0,32768) for 8-wave acc dump, [33792,+4096) for sums.
// ==========================================================================
__global__ __launch_bounds__(512) void crf_iter_kernel(
    const float* __restrict__ qfeatA,
    const float* __restrict__ qsoa,
    const half_t* __restrict__ qin,
    half_t* __restrict__ qout,
    const float* __restrict__ ut_,
    half_t* __restrict__ kmat,
    float* __restrict__ outq,
    const float* __restrict__ gconst,
    int first, int last)
{
    __shared__ __align__(16) char lds[46080];
    half_t* qlsA = (half_t*)lds;                 // 16896 B
    half_t* qlsB = (half_t*)(lds + 16896);       // 16896 B
    float*  qsoA = (float*)(lds + 33792);        // 6144 B
    float*  qsoB = (float*)(lds + 39936);        // 6144 B

    int b = blockIdx.x;
    int n = b & 1, ptA = b >> 1;                 // ptA in [0,128)
    int tid = threadIdx.x;
    int l = tid & 63, v = tid >> 6;              // 8 waves
    int kq = (l >> 4) * 8;
    int qoff = v * 32 + kq;                      // this wave's k-slice in chunk

    // zero rows 21..31 of both q-LDS buffers (B-operand channels 21..31)
    for (int i = tid; i < 2 * 363; i += 512) {
        int bi = (i >= 363);
        int j = i - bi * 363;
        int c = 21 + j / 33, g = j % 33;
        half_t* q = bi ? qlsB : qlsA;
        *(h8*)(q + c * QLS_STRIDE + g * 8) = (h8)(half_t)0.f;
    }
    // stage chunk 0 into A buffers
    for (int i = tid; i < 672; i += 512) {
        int c = i >> 5, g = i & 31;
        *(h8*)(qlsA + c * QLS_STRIDE + g * 8) =
            *(const h8*)(qin + (size_t)(n * 24 + c) * NP + g * 8);
    }
    if (first) {
        for (int i = tid; i < 384; i += 512) {
            int d = i >> 6, g = i & 63;
            *(f4*)(qsoA + d * CHUNK + g * 4) =
                *(const f4*)(qsoa + (size_t)d * 8192 + n * NP + g * 4);
        }
    }

    // p-side features + pixel coords (build path only)
    f2 pf2[2][5], ph2[2];
    int yp[2] = {0, 0}, xp[2] = {0, 0};
    float C2p1 = 0.f;
    if (first) {
        C2p1 = gconst[0];
        #pragma unroll
        for (int mt = 0; mt < 2; ++mt) {
            int pp = ptA * 32 + mt * 16 + (l & 15);
            const float* fp = qfeatA + (size_t)(n * NP + pp) * 8;
            #pragma unroll
            for (int i = 0; i < 5; ++i) { float vv = fp[i] * RL2E; pf2[mt][i] = (f2){vv, vv}; }
            ph2[mt] = (f2){fp[5], fp[5]};
            yp[mt] = pp >> 6; xp[mt] = pp & 63;
        }
    }

    f4 acc[2][2];
    acc[0][0] = (f4)0.f; acc[0][1] = (f4)0.f;
    acc[1][0] = (f4)0.f; acc[1][1] = (f4)0.f;

    // fragment addressing: block-local, self-consistent build/apply
    size_t fb = (size_t)b * (16 * 16 * 512);
    h8 kv0 = (h8)(half_t)0.f, kv1 = (h8)(half_t)0.f;   // apply-path prefetch regs
    if (!first) {
        kv0 = *(const h8*)(kmat + fb + (size_t)(v * 2 + 0) * 512 + l * 8);
        kv1 = *(const h8*)(kmat + fb + (size_t)(v * 2 + 1) * 512 + l * 8);
    }
    __syncthreads();

    for (int s = 0; s < 16; ++s) {
        half_t* qc = (s & 1) ? qlsB : qlsA;
        half_t* qn = (s & 1) ? qlsA : qlsB;
        float*  sc = (s & 1) ? qsoB : qsoA;
        float*  sn = (s & 1) ? qsoA : qsoB;

        // stage chunk s+1 into the other buffer (overlaps compute of s)
        if (s < 15) {
            for (int i = tid; i < 672; i += 512) {
                int c = i >> 5, g = i & 31;
                *(h8*)(qn + c * QLS_STRIDE + g * 8) =
                    *(const h8*)(qin + (size_t)(n * 24 + c) * NP + (s + 1) * CHUNK + g * 8);
            }
            if (first) {
                for (int i = tid; i < 384; i += 512) {
                    int d = i >> 6, g = i & 63;
                    *(f4*)(sn + d * CHUNK + g * 4) =
                        *(const f4*)(qsoa + (size_t)d * 8192 + n * NP + (s + 1) * CHUNK + g * 4);
                }
            }
        }

        h8 kvc0, kvc1;
        if (first) {
            h8 kv[2];
            #pragma unroll
            for (int hf = 0; hf < 2; ++hf) {
                f4 qf0 = *(const f4*)(sc + 0 * CHUNK + qoff + hf * 4);
                f4 qf1 = *(const f4*)(sc + 1 * CHUNK + qoff + hf * 4);
                f4 qf2 = *(const f4*)(sc + 2 * CHUNK + qoff + hf * 4);
                f4 qf3 = *(const f4*)(sc + 3 * CHUNK + qoff + hf * 4);
                f4 qf4 = *(const f4*)(sc + 4 * CHUNK + qoff + hf * 4);
                f4 qf5 = *(const f4*)(sc + 5 * CHUNK + qoff + hf * 4);
                #pragma unroll
                for (int pr = 0; pr < 2; ++pr) {
                    f2 q0 = {qf0[2*pr], qf0[2*pr+1]};
                    f2 q1 = {qf1[2*pr], qf1[2*pr+1]};
                    f2 q2 = {qf2[2*pr], qf2[2*pr+1]};
                    f2 q3 = {qf3[2*pr], qf3[2*pr+1]};
                    f2 q4 = {qf4[2*pr], qf4[2*pr+1]};
                    f2 qh2 = {qf5[2*pr], qf5[2*pr+1]};
                    #pragma unroll
                    for (int mt = 0; mt < 2; ++mt) {
                        f2 e = pk_add(qh2, ph2[mt]);
                        e = pk_fma(pf2[mt][0], q0, e);
                        e = pk_fma(pf2[mt][1], q1, e);
                        e = pk_fma(pf2[mt][2], q2, e);
                        e = pk_fma(pf2[mt][3], q3, e);
                        e = pk_fma(pf2[mt][4], q4, e);
                        #pragma unroll
                        for (int jj = 0; jj < 2; ++jj) {
                            int qpix = s * CHUNK + qoff + hf * 4 + pr * 2 + jj;
                            int dy = yp[mt] - (qpix >> 6);
                            int dx = xp[mt] - (qpix & 63);
                            float ge = 0.f;
                            if ((unsigned)(dy + KR) <= 2u * KR && (unsigned)(dx + KR) <= 2u * KR)
                                ge = EXP2F((float)(dy * dy + dx * dx) * GEXPC + C2p1);
                            // M = 4*K + 2*G2d : exp2(e+2) + exp2(g+1)
                            float mval = EXP2F(e[jj] + 2.0f) + ge;
                            kv[mt][hf * 4 + pr * 2 + jj] = (half_t)mval;
                        }
                    }
                }
            }
            kvc0 = kv[0]; kvc1 = kv[1];
            *(h8*)(kmat + fb + (size_t)(s * 16 + v * 2 + 0) * 512 + l * 8) = kvc0;
            *(h8*)(kmat + fb + (size_t)(s * 16 + v * 2 + 1) * 512 + l * 8) = kvc1;
        } else {
            kvc0 = kv0; kvc1 = kv1;
            if (s < 15) {
                kv0 = *(const h8*)(kmat + fb + (size_t)((s + 1) * 16 + v * 2 + 0) * 512 + l * 8);
                kv1 = *(const h8*)(kmat + fb + (size_t)((s + 1) * 16 + v * 2 + 1) * 512 + l * 8);
            }
        }

        h8 bf0 = *(const h8*)(qc + (size_t)(l & 15) * QLS_STRIDE + qoff);
        h8 bf1 = *(const h8*)(qc + (size_t)(16 + (l & 15)) * QLS_STRIDE + qoff);
        acc[0][0] = MFMA16(kvc0, bf0, acc[0][0]);
        acc[0][1] = MFMA16(kvc0, bf1, acc[0][1]);
        acc[1][0] = MFMA16(kvc1, bf0, acc[1][0]);
        acc[1][1] = MFMA16(kvc1, bf1, acc[1][1]);
        __syncthreads();
    }

    // ---- cross-wave reduction (fp32, no global round-trip) ----
    f4* redf = (f4*)lds;                          // 2048 f4 = 32 KB
    #pragma unroll
    for (int mt = 0; mt < 2; ++mt)
        #pragma unroll
        for (int cht = 0; cht < 2; ++cht)
            redf[(size_t)(v * 4 + mt * 2 + cht) * 64 + l] = acc[mt][cht];
    __syncthreads();

    f4* red2 = (f4*)(lds + 33792);                // 256 f4 = 4 KB
    if (tid < 256) {
        int mc = tid >> 6, ll = tid & 63;
        f4 sum = redf[(size_t)(0 * 4 + mc) * 64 + ll];
        #pragma unroll
        for (int vv = 1; vv < 8; ++vv)
            sum = sum + redf[(size_t)(vv * 4 + mc) * 64 + ll];
        red2[mc * 64 + ll] = sum;
    }
    __syncthreads();

    // ---- softmax update for this block's 32 p's ----
    if (tid < 32) {
        int pl = tid;
        int p = ptA * 32 + pl;
        int gid = n * NP + p;
        int mt = pl >> 4, prow = pl & 15;
        int lg = prow >> 2, reg = prow & 3;
        const float* ut = ut_ + (size_t)gid * 24;
        const float* r2 = (const float*)red2;
        float e[NC];
        float m = -1e30f;
        #pragma unroll
        for (int c = 0; c < NC; ++c) {
            int cht = c >> 4, chL = c & 15;
            float qb = r2[((mt * 2 + cht) * 64 + (lg * 16 + chL)) * 4 + reg];
            float li = ut[c] + qb;               // M already folds 4x / 2x
            e[c] = li;
            m = fmaxf(m, li);
        }
        float ssum = 0.f;
        #pragma unroll
        for (int c = 0; c < NC; ++c) { float vv = EXP2F(L2E * (e[c] - m)); e[c] = vv; ssum += vv; }
        float inv = 1.0f / ssum;
        if (last) {
            #pragma unroll
            for (int c = 0; c < NC; ++c)
                outq[(size_t)(n * NC + c) * NP + p] = e[c] * inv;
        } else {
            #pragma unroll
            for (int c = 0; c < NC; ++c)
                qout[(size_t)(n * 24 + c) * NP + p] = (half_t)(e[c] * inv);
        }
    }
}

extern "C" void kernel_launch(void* const* d_in, const int* in_sizes, int n_in,
                              void* d_out, int out_size, void* d_ws, size_t ws_size,
                              hipStream_t stream)
{
    const float* unary = (const float*)d_in[0];
    const float* ref   = (const float*)d_in[1];
    const float* kstd  = (const float*)d_in[3];
    float* ws   = (float*)d_ws;
    float* outq = (float*)d_out;

    const float* qfeatA = ws + OFF_QFEAT;
    const float* qsoa   = ws + OFF_QSOA;
    const float* ut     = ws + OFF_UT;
    half_t* qA   = (half_t*)(ws + OFF_QA);
    half_t* qB   = (half_t*)(ws + OFF_QB);
    const float* gconst = ws + OFF_G;
    half_t* kmat = (half_t*)(ws + OFF_KMAT);

    setup_kernel<<<32, 256, 0, stream>>>(unary, ref, kstd, ws);
    for (int it = 0; it < NUM_ITER; ++it) {
        half_t* qin  = (it & 1) ? qB : qA;
        half_t* qout = (it & 1) ? qA : qB;
        crf_iter_kernel<<<NBATCH * 128, 512, 0, stream>>>(
            qfeatA, qsoa, qin, qout, ut, kmat, outq, gconst,
            it == 0 ? 1 : 0, it == NUM_ITER - 1 ? 1 : 0);
    }
}

// Round 5
// 145.075 us; speedup vs baseline: 1.2809x; 1.2809x over previous
//
#include <hip/hip_runtime.h>
#include <math.h>

#ifndef __has_builtin
#define __has_builtin(x) 0
#endif
#if __has_builtin(__builtin_amdgcn_exp2f)
#define EXP2F(x) __builtin_amdgcn_exp2f(x)
#else
#define EXP2F(x) exp2f(x)
#endif

#define L2E  1.44269504088896340736f
#define RL2E 0.69314718055994530942f

#define NBATCH 2
#define NC 21
#define NP 4096
#define KR 35
#define NUM_ITER 5

typedef _Float16 half_t;
typedef _Float16 h8 __attribute__((ext_vector_type(8)));
typedef _Float16 h4 __attribute__((ext_vector_type(4)));
typedef float f4 __attribute__((ext_vector_type(4)));
typedef float f2 __attribute__((ext_vector_type(2)));
#define MFMA16(a, b, c) __builtin_amdgcn_mfma_f32_16x16x32_f16((a), (b), (c), 0, 0, 0)

// packed fp32 math via inline asm (builtin lowering NaN'd — R8/R13)
static __device__ __forceinline__ f2 pk_fma(f2 a, f2 b, f2 c) {
    f2 d;
    asm volatile("v_pk_fma_f32 %0, %1, %2, %3" : "=v"(d) : "v"(a), "v"(b), "v"(c));
    return d;
}
static __device__ __forceinline__ f2 pk_add(f2 a, f2 b) {
    f2 d;
    asm volatile("v_pk_add_f32 %0, %1, %2" : "=v"(d) : "v"(a), "v"(b));
    return d;
}

// ---- tiling: R10-proven (best measured: 155.0 us) ----
#define PTILE 128          // p per block (2 m-tiles per wave)
#define NPT   32
#define SQ    16           // q-splits -> chunk = 256 q
#define CHUNK 256
#define STEPS 8            // CHUNK/32
#define NBBIL (NBATCH * NPT * SQ)   // 1024
#define NBCONV (NBATCH * NC)        // 42
#define SEG_HALVES 256

// ---- ws layout (float offsets) ----
#define OFF_QFEAT 0                  // [NB*P][8] fp32 AoS {L*f0..L*f4, h, 0,0}
#define OFF_QSOA  65536              // [6][NB*P] fp32 SoA planes
#define OFF_UT    114688             // [NB*P][24] fp32 log-unary
#define OFF_QSF   311296             // [NB][21][P] fp32 spatial out
#define OFF_G     483328             // [64][64] fp16 band-gaussian
#define OFF_QH16  485376             // [NB][24][P] fp16 planar q
#define OFF_PART  845824             // [SQ][1024 segs][256] fp16 partials

// ---- LDS: bilat 23040 B (SoA 6144 + qls 16896), conv 27648 B ----
#define LDS_BYTES 27648
#define QLS_STRIDE 264     // halves (256 data + 8 pad) — R6-proven banking

__global__ __launch_bounds__(256) void setup_kernel(
    const float* __restrict__ unary, const float* __restrict__ ref,
    const float* __restrict__ kstd, float* __restrict__ ws,
    float* __restrict__ outq)
{
    int gid = blockIdx.x * 256 + threadIdx.x;
    if (gid < 4096) {
        float s = 0.f;
        for (int t = -KR; t <= KR; ++t) s += expf(-(float)(t * t) * (1.0f / 72.0f));
        int y = gid >> 6, yp = gid & 63;
        int d = y - yp;
        float v = (d >= -KR && d <= KR) ? expf(-(float)(d * d) * (1.0f / 72.0f)) / s : 0.f;
        ((half_t*)(ws + OFF_G))[gid] = (half_t)v;
    }
    if (gid >= NBATCH * NP) return;
    int n = gid >> 12, p = gid & (NP - 1);
    int y = p >> 6, x = p & 63;
    float k0 = kstd[0], k1 = kstd[1], k2 = kstd[2], k3 = kstd[3], k4 = kstd[4];
    const float* rp = ref + n * 3 * NP + p;
    float f0 = (float)y / k0;
    float f1 = (float)x / k1;
    float f2_ = rp[0]      / k2;
    float f3 = rp[NP]     / k3;
    float f4_ = rp[2 * NP] / k4;
    float sq = f0*f0 + f1*f1 + f2_*f2_ + f3*f3 + f4_*f4_;
    float h  = -0.5f * L2E * sq;       // exp2 exponent offset
    float* qf = ws + OFF_QFEAT + gid * 8;
    qf[0]=L2E*f0; qf[1]=L2E*f1; qf[2]=L2E*f2_; qf[3]=L2E*f3; qf[4]=L2E*f4_;
    qf[5]=h; qf[6]=0.f; qf[7]=0.f;
    float* qs = ws + OFF_QSOA;
    qs[0*8192 + gid] = L2E*f0;  qs[1*8192 + gid] = L2E*f1;
    qs[2*8192 + gid] = L2E*f2_; qs[3*8192 + gid] = L2E*f3;
    qs[4*8192 + gid] = L2E*f4_; qs[5*8192 + gid] = h;

    float U[NC], e[NC];
    const float* up = unary + n * NC * NP + p;
    float m = -1e30f;
    for (int c = 0; c < NC; ++c) {
        float u = up[c * NP];
        u = fminf(fmaxf(u, 1e-5f), 1.0f);
        U[c] = logf(u);
        m = fmaxf(m, U[c]);
    }
    float ssum = 0.f;
    for (int c = 0; c < NC; ++c) { e[c] = EXP2F(L2E * (U[c] - m)); ssum += e[c]; }
    float inv = 1.0f / ssum;
    float* ut = ws + OFF_UT + gid * 24;
    half_t* qh = (half_t*)(ws + OFF_QH16);
    for (int c = 0; c < NC; ++c) {
        float qv = e[c] * inv;
        ut[c] = U[c];
        qh[(n * 24 + c) * NP + p] = (half_t)qv;
        outq[(n * NC + c) * NP + p] = qv;
    }
    ut[21] = 0.f; ut[22] = 0.f; ut[23] = 0.f;
    qh[(n * 24 + 21) * NP + p] = (half_t)0.f;
    qh[(n * 24 + 22) * NP + p] = (half_t)0.f;
    qh[(n * 24 + 23) * NP + p] = (half_t)0.f;
}

// L1: blocks [0,1024): bilateral.  blocks [1024,1066): separable conv.
// (verbatim R10-proven kernel — 155.0 us baseline)
__global__ __launch_bounds__(256) void bilat_conv_kernel(
    const float* __restrict__ qfeatA,     // AoS (p side)
    const float* __restrict__ qsoa,       // SoA planes (q side)
    const half_t* __restrict__ qh16,
    const half_t* __restrict__ gmat,
    half_t* __restrict__ part,
    float* __restrict__ qsf)
{
    __shared__ __align__(16) char lds[LDS_BYTES];
    int b = blockIdx.x;
    int tid = threadIdx.x;
    int l = tid & 63, w = tid >> 6;

    if (b < NBBIL) {
        int n  = b & 1;
        int pt = (b >> 1) & (NPT - 1);
        int s  = b >> 6;                           // 0..15
        float*  qsoaS = (float*)lds;               // [6][256]  6 KB
        half_t* qls   = (half_t*)(lds + 6144);     // [32][264] 16896 B

        // stage SoA q-features (coalesced per plane)
        for (int i = tid; i < 6 * (CHUNK / 4); i += 256) {   // 384 float4
            int d = i >> 6, g = i & 63;
            *(f4*)(qsoaS + d * CHUNK + g * 4) =
                *(const f4*)(qsoa + (size_t)d * 8192 + n * NP + s * CHUNK + g * 4);
        }
        // stage q-probs fp16 rows 0..20; zero rows 21..31
        for (int i = tid; i < 21 * (CHUNK / 8); i += 256) {  // 672 h8
            int c = i >> 5, g = i & 31;
            *(h8*)(qls + c * QLS_STRIDE + g * 8) =
                *(const h8*)(qh16 + (size_t)(n * 24 + c) * NP + s * CHUNK + g * 8);
        }
        for (int i = tid; i < 11 * 33; i += 256) {           // 363 h8 zeros
            int c = 21 + i / 33, g = i % 33;
            *(h8*)(qls + c * QLS_STRIDE + g * 8) = (h8)(half_t)0.f;
        }
        // p-side features: wave w owns m-tiles w*2, w*2+1; lane row = l&15
        // broadcast pairs hoisted for packed math
        f2 pf2[2][5], ph2[2];
        #pragma unroll
        for (int mt = 0; mt < 2; ++mt) {
            const float* fp = qfeatA + (size_t)(n * NP + pt * PTILE + (w * 2 + mt) * 16 + (l & 15)) * 8;
            #pragma unroll
            for (int i = 0; i < 5; ++i) {
                float v = fp[i] * RL2E;
                pf2[mt][i] = (f2){v, v};
            }
            ph2[mt] = (f2){fp[5], fp[5]};
        }
        f4 acc[2][2];
        #pragma unroll
        for (int mt = 0; mt < 2; ++mt) { acc[mt][0] = (f4)0.f; acc[mt][1] = (f4)0.f; }
        int kq = (l >> 4) * 8;
        __syncthreads();

        for (int step = 0; step < STEPS; ++step) {
            int qbase = step * 32 + kq;
            h8 kv[2];
            #pragma unroll
            for (int hf = 0; hf < 2; ++hf) {
                // conflict-free b128 quad reads: this lane's 4 q's, all 6 features
                f4 qf0 = *(const f4*)(qsoaS + 0 * CHUNK + qbase + hf * 4);
                f4 qf1 = *(const f4*)(qsoaS + 1 * CHUNK + qbase + hf * 4);
                f4 qf2 = *(const f4*)(qsoaS + 2 * CHUNK + qbase + hf * 4);
                f4 qf3 = *(const f4*)(qsoaS + 3 * CHUNK + qbase + hf * 4);
                f4 qf4 = *(const f4*)(qsoaS + 4 * CHUNK + qbase + hf * 4);
                f4 qf5 = *(const f4*)(qsoaS + 5 * CHUNK + qbase + hf * 4);
                // packed fp32 fma via asm: two q's per instruction
                #pragma unroll
                for (int pr = 0; pr < 2; ++pr) {
                    f2 q0 = {qf0[2*pr], qf0[2*pr+1]};
                    f2 q1 = {qf1[2*pr], qf1[2*pr+1]};
                    f2 q2 = {qf2[2*pr], qf2[2*pr+1]};
                    f2 q3 = {qf3[2*pr], qf3[2*pr+1]};
                    f2 q4 = {qf4[2*pr], qf4[2*pr+1]};
                    f2 qh2 = {qf5[2*pr], qf5[2*pr+1]};
                    #pragma unroll
                    for (int mt = 0; mt < 2; ++mt) {
                        f2 e = pk_add(qh2, ph2[mt]);
                        e = pk_fma(pf2[mt][0], q0, e);
                        e = pk_fma(pf2[mt][1], q1, e);
                        e = pk_fma(pf2[mt][2], q2, e);
                        e = pk_fma(pf2[mt][3], q3, e);
                        e = pk_fma(pf2[mt][4], q4, e);
                        kv[mt][hf * 4 + pr * 2]     = (half_t)EXP2F(e[0]);
                        kv[mt][hf * 4 + pr * 2 + 1] = (half_t)EXP2F(e[1]);
                    }
                }
            }
            h8 bf0 = *(const h8*)(qls + (size_t)(l & 15) * QLS_STRIDE + qbase);
            h8 bf1 = *(const h8*)(qls + (size_t)(16 + (l & 15)) * QLS_STRIDE + qbase);
            #pragma unroll
            for (int mt = 0; mt < 2; ++mt) {
                acc[mt][0] = MFMA16(kv[mt], bf0, acc[mt][0]);
                acc[mt][1] = MFMA16(kv[mt], bf1, acc[mt][1]);
            }
        }
        // epilogue: raw C-fragment partials, fp16, coalesced b64
        #pragma unroll
        for (int mt = 0; mt < 2; ++mt) {
            #pragma unroll
            for (int cht = 0; cht < 2; ++cht) {
                int segFlat = ((((s * 2 + n) * NPT + pt) * 4 + w) * 2 + mt) * 2 + cht;
                h4 hv;
                hv[0] = (half_t)acc[mt][cht][0];
                hv[1] = (half_t)acc[mt][cht][1];
                hv[2] = (half_t)acc[mt][cht][2];
                hv[3] = (half_t)acc[mt][cht][3];
                *(h4*)(part + (size_t)segFlat * SEG_HALVES + l * 4) = hv;
            }
        }
    } else {
        // ---- conv block: one (n,c); qsf = G * Q * G ----
        int cb = b - NBBIL;
        int n = cb / NC, c = cb % NC;
        half_t* qt = (half_t*)lds;
        half_t* gl = (half_t*)(lds + 9216);
        half_t* dl = (half_t*)(lds + 18432);

        for (int i = tid; i < 512; i += 256) {
            int row = i >> 3, g = i & 7;
            *(h8*)(gl + row * 72 + g * 8) = *(const h8*)(gmat + row * 64 + g * 8);
        }
        const half_t* qsrc = qh16 + (size_t)(n * 24 + c) * NP;
        for (int i = tid; i < 512; i += 256) {
            int row = i >> 3, g = i & 7;
            h8 v = *(const h8*)(qsrc + row * 64 + g * 8);
            #pragma unroll
            for (int k = 0; k < 8; ++k) qt[(g * 8 + k) * 72 + row] = v[k];
        }
        __syncthreads();

        int m0 = w * 16;
        f4 acc1[4];
        #pragma unroll
        for (int nt = 0; nt < 4; ++nt) acc1[nt] = (f4)0.f;
        #pragma unroll
        for (int ks = 0; ks < 2; ++ks) {
            h8 af = *(const h8*)(gl + (size_t)(m0 + (l & 15)) * 72 + ks * 32 + (l >> 4) * 8);
            #pragma unroll
            for (int nt = 0; nt < 4; ++nt) {
                h8 bf = *(const h8*)(qt + (size_t)(nt * 16 + (l & 15)) * 72 + ks * 32 + (l >> 4) * 8);
                acc1[nt] = MFMA16(af, bf, acc1[nt]);
            }
        }
        #pragma unroll
        for (int nt = 0; nt < 4; ++nt)
            #pragma unroll
            for (int r = 0; r < 4; ++r)
                dl[(size_t)(m0 + (l >> 4) * 4 + r) * 72 + nt * 16 + (l & 15)] = (half_t)acc1[nt][r];
        __syncthreads();

        f4 acc2[4];
        #pragma unroll
        for (int nt = 0; nt < 4; ++nt) acc2[nt] = (f4)0.f;
        #pragma unroll
        for (int ks = 0; ks < 2; ++ks) {
            h8 af = *(const h8*)(dl + (size_t)(m0 + (l & 15)) * 72 + ks * 32 + (l >> 4) * 8);
            #pragma unroll
            for (int nt = 0; nt < 4; ++nt) {
                h8 bf = *(const h8*)(gl + (size_t)(nt * 16 + (l & 15)) * 72 + ks * 32 + (l >> 4) * 8);
                acc2[nt] = MFMA16(af, bf, acc2[nt]);
            }
        }
        float* dst = qsf + (size_t)(n * NC + c) * NP;
        #pragma unroll
        for (int nt = 0; nt < 4; ++nt)
            #pragma unroll
            for (int r = 0; r < 4; ++r)
                dst[(size_t)(m0 + (l >> 4) * 4 + r) * 64 + nt * 16 + (l & 15)] = acc2[nt][r];
    }
}

// L2+L3 merged: reduce fp16 partials over s, then per-pixel softmax update.
// NEW vs legacy: 256 blocks (4x CU coverage) = (n, pt, wave-quarter wq);
// the 16 s-partials are preloaded into registers (independent loads, one
// latency) then summed in the ORIGINAL s-order -> bit-identical to legacy.
__global__ __launch_bounds__(256) void reduce_update_kernel(
    const half_t* __restrict__ part, const float* __restrict__ ut_,
    const float* __restrict__ qsf, float* __restrict__ outq,
    half_t* __restrict__ qh16, int last)
{
    __shared__ float red[1024];    // 4 segs * 256
    int rb = blockIdx.x;           // [0,256)
    int tid = threadIdx.x;
    int n = rb & 1, pt = (rb >> 1) & (NPT - 1), wq = rb >> 6;
    int lseg = tid >> 6, l = tid & 63;

    // seg = ((s*2+n)*NPT+pt)*16 + wq*4 + lseg ; stride over s = 1024 segs
    const half_t* pb = part
        + (size_t)(((n * NPT + pt) * 4 + wq) * 4 + lseg) * SEG_HALVES
        + (size_t)l * 4;
    h4 vv[16];
    #pragma unroll
    for (int s = 0; s < SQ; ++s)
        vv[s] = *(const h4*)(pb + (size_t)s * 1024 * SEG_HALVES);

    float a0 = 0.f, a1 = 0.f, a2 = 0.f, a3 = 0.f;
    #pragma unroll
    for (int s = 0; s < SQ; ++s) {            // same s-order as legacy
        a0 += (float)vv[s][0]; a1 += (float)vv[s][1];
        a2 += (float)vv[s][2]; a3 += (float)vv[s][3];
    }
    *(f4*)(red + tid * 4) = (f4){a0, a1, a2, a3};
    __syncthreads();

    if (tid < 32) {
        int pp = tid;
        int p = pt * PTILE + wq * 32 + pp;
        int gid = n * NP + p;
        int mtl = pp >> 4, mrow = pp & 15;
        int lg2 = mrow >> 2, reg = mrow & 3;

        const float* ut = ut_ + (size_t)gid * 24;
        const float* qs = qsf + (size_t)n * NC * NP + p;
        float e[NC];
        float m = -1e30f;
        #pragma unroll
        for (int c = 0; c < NC; ++c) {
            int cht = c >> 4, chL = c & 15;
            float qb = red[(mtl * 2 + cht) * 256 + (lg2 * 16 + chL) * 4 + reg];
            float li = ut[c] + 4.0f * qb + 2.0f * qs[c * NP];
            e[c] = li;
            m = fmaxf(m, li);
        }
        float ssum = 0.f;
        #pragma unroll
        for (int c = 0; c < NC; ++c) { float v = EXP2F(L2E * (e[c] - m)); e[c] = v; ssum += v; }
        float inv = 1.0f / ssum;
        if (last) {
            #pragma unroll
            for (int c = 0; c < NC; ++c)
                outq[(size_t)(n * NC + c) * NP + p] = e[c] * inv;
        } else {
            #pragma unroll
            for (int c = 0; c < NC; ++c)
                qh16[(size_t)(n * 24 + c) * NP + p] = (half_t)(e[c] * inv);
        }
    }
}

extern "C" void kernel_launch(void* const* d_in, const int* in_sizes, int n_in,
                              void* d_out, int out_size, void* d_ws, size_t ws_size,
                              hipStream_t stream)
{
    const float* unary = (const float*)d_in[0];
    const float* ref   = (const float*)d_in[1];
    const float* kstd  = (const float*)d_in[3];
    float* ws   = (float*)d_ws;
    float* outq = (float*)d_out;

    const float*  qfeatA = ws + OFF_QFEAT;
    const float*  qsoa   = ws + OFF_QSOA;
    float*        ut     = ws + OFF_UT;
    float*        qsf    = ws + OFF_QSF;
    const half_t* gmat   = (const half_t*)(ws + OFF_G);
    half_t*       qh16   = (half_t*)(ws + OFF_QH16);
    half_t*       part   = (half_t*)(ws + OFF_PART);

    setup_kernel<<<32, 256, 0, stream>>>(unary, ref, kstd, ws, outq);
    for (int it = 0; it < NUM_ITER; ++it) {
        bilat_conv_kernel<<<NBBIL + NBCONV, 256, 0, stream>>>(
            qfeatA, qsoa, qh16, gmat, part, qsf);
        reduce_update_kernel<<<256, 256, 0, stream>>>(
            part, ut, qsf, outq, qh16, it == NUM_ITER - 1 ? 1 : 0);
    }
}